// Round 12
// baseline (810.882 us; speedup 1.0000x reference)
//
#include <hip/hip_runtime.h>
#include <math.h>

#define N_NODES_C 16384
#define N_EDGES_C 196608
#define MAX_TILES 32768

typedef short bf16x8 __attribute__((ext_vector_type(8)));
typedef unsigned short u16x8 __attribute__((ext_vector_type(8)));
typedef float f32x4 __attribute__((ext_vector_type(4)));
typedef float f32x8 __attribute__((ext_vector_type(8)));

__device__ __forceinline__ float silu_f(float x) {
  return x * __builtin_amdgcn_rcpf(1.0f + __expf(-x));
}

// ---------------- CSR build ----------------
__global__ void k_count(const int* __restrict__ rcv, int* __restrict__ counts) {
  int e = blockIdx.x * 256 + threadIdx.x;
  atomicAdd(&counts[rcv[e]], 1);
}

// dual prefix sum: exact CSR offsets AND tile offsets (ceil(cnt/16))
__global__ __launch_bounds__(1024) void k_scan(const int* __restrict__ counts,
                                               int* __restrict__ row_start,
                                               int* __restrict__ cursor,
                                               int* __restrict__ tstart) {
  __shared__ int s1a[1024];
  __shared__ int s2a[1024];
  const int tid = threadIdx.x;
  int loc[16];
  int s1 = 0, s2 = 0;
#pragma unroll
  for (int i = 0; i < 16; ++i) {
    loc[i] = counts[tid * 16 + i];
    s1 += loc[i];
    s2 += (loc[i] + 15) >> 4;
  }
  s1a[tid] = s1;
  s2a[tid] = s2;
  __syncthreads();
  for (int off = 1; off < 1024; off <<= 1) {
    int t1 = (tid >= off) ? s1a[tid - off] : 0;
    int t2 = (tid >= off) ? s2a[tid - off] : 0;
    __syncthreads();
    s1a[tid] += t1;
    s2a[tid] += t2;
    __syncthreads();
  }
  int e1 = s1a[tid] - s1, e2 = s2a[tid] - s2;
#pragma unroll
  for (int i = 0; i < 16; ++i) {
    row_start[tid * 16 + i] = e1;
    cursor[tid * 16 + i] = e1;
    tstart[tid * 16 + i] = e2;
    e1 += loc[i];
    e2 += (loc[i] + 15) >> 4;
  }
  if (tid == 1023) {
    row_start[N_NODES_C] = e1;
    tstart[N_NODES_C] = e2;
  }
}

__global__ void k_fill(const int* __restrict__ rcv, int* __restrict__ cursor,
                       int* __restrict__ elist) {
  int e = blockIdx.x * 256 + threadIdx.x;
  int slot = atomicAdd(&cursor[rcv[e]], 1);
  elist[slot] = e;
}

// tile descriptors: x = node | len<<20 | multi<<31 ; y = p0 (CSR offset)
__global__ void k_tiles(const int* __restrict__ row_start, const int* __restrict__ tstart,
                        int2* __restrict__ tdesc) {
  const int n = blockIdx.x * 256 + threadIdx.x;
  const int e0 = row_start[n], e1 = row_start[n + 1];
  const int cnt = e1 - e0;
  const int nt = (cnt + 15) >> 4;
  const int t0 = tstart[n];
  const unsigned mbit = (nt > 1) ? 0x80000000u : 0u;
  for (int j = 0; j < nt; ++j) {
    int len = cnt - 16 * j;
    if (len > 16) len = 16;
    tdesc[t0 + j] = make_int2((int)((unsigned)n | ((unsigned)len << 20) | mbit), e0 + 16 * j);
  }
}

// ---------------- node element id + embedding ----------------
__global__ void k_elem(const float* __restrict__ attrs, int* __restrict__ elem) {
  int n = blockIdx.x * 256 + threadIdx.x;
  const float* a = attrs + n * 8;
  int best = 0;
  float bv = a[0];
#pragma unroll
  for (int z = 1; z < 8; ++z) {
    if (a[z] > bv) { bv = a[z]; best = z; }
  }
  elem[n] = best;
}

__global__ void k_embed(const float* __restrict__ attrs, const float* __restrict__ Wemb,
                        float* __restrict__ scal0, float* __restrict__ nf) {
  int gid = blockIdx.x * 256 + threadIdx.x;  // N*32 threads
  int n = gid >> 5, c = gid & 31;
  float s = 0.f;
#pragma unroll
  for (int z = 0; z < 8; ++z) s = fmaf(attrs[n * 8 + z], Wemb[z * 32 + c], s);
  scal0[gid] = s;
  float* row = nf + (size_t)n * 512 + c * 16;
  *(float4*)&row[0] = make_float4(s, 0.f, 0.f, 0.f);
  *(float4*)&row[4] = make_float4(0.f, 0.f, 0.f, 0.f);
  *(float4*)&row[8] = make_float4(0.f, 0.f, 0.f, 0.f);
  *(float4*)&row[12] = make_float4(0.f, 0.f, 0.f, 0.f);
}

// ---------------- per-edge radial MLP via MFMA (+SH, +s-edge) -------------
// Wave = 16 edges (one MFMA M-tile), 6 groups per wave, barrier-free.
__global__ __launch_bounds__(256, 2) void k_radial(
    const float* __restrict__ pos, const float* __restrict__ shifts,
    const int* __restrict__ snd, const int* __restrict__ rcv,
    const int* __restrict__ elist, const float* __restrict__ scal,
    const float* __restrict__ W1g, const float* __restrict__ W2g,
    const float* __restrict__ W3g, unsigned short* __restrict__ h3,
    float* __restrict__ sedge, float* __restrict__ Yout, const int writeY) {
  __shared__ unsigned tb[4][64 * 17];
  const int wid = threadIdx.x >> 6, lane = threadIdx.x & 63;
  const int grp = lane >> 4, lm = lane & 15;
  unsigned* tw = tb[wid];

  // ---- weight B-fragments (hi/lo bf16), loaded once per wave ----
  bf16x8 b1hi[4], b1lo[4];
#pragma unroll
  for (int t = 0; t < 4; ++t) {
#pragma unroll
    for (int j = 0; j < 8; ++j) {
      const float wv = (grp == 0) ? W1g[j * 64 + t * 16 + lm] : 0.f;
      const unsigned hb = __float_as_uint(wv) & 0xFFFF0000u;
      b1hi[t][j] = (short)(hb >> 16);
      b1lo[t][j] = (short)(__float_as_uint(wv - __uint_as_float(hb)) >> 16);
    }
  }
  bf16x8 b2hi[4][2], b2lo[4][2], b3hi[4][2], b3lo[4][2];
#pragma unroll
  for (int t = 0; t < 4; ++t) {
#pragma unroll
    for (int kf = 0; kf < 2; ++kf) {
#pragma unroll
      for (int j = 0; j < 8; ++j) {
        const int widx = (kf * 32 + grp * 8 + j) * 64 + t * 16 + lm;
        {
          const float wv = W2g[widx];
          const unsigned hb = __float_as_uint(wv) & 0xFFFF0000u;
          b2hi[t][kf][j] = (short)(hb >> 16);
          b2lo[t][kf][j] = (short)(__float_as_uint(wv - __uint_as_float(hb)) >> 16);
        }
        {
          const float wv = W3g[widx];
          const unsigned hb = __float_as_uint(wv) & 0xFFFF0000u;
          b3hi[t][kf][j] = (short)(hb >> 16);
          b3lo[t][kf][j] = (short)(__float_as_uint(wv - __uint_as_float(hb)) >> 16);
        }
      }
    }
  }

  const int wv_id = blockIdx.x * 4 + wid;  // 0..2047
  for (int g = 0; g < 6; ++g) {
    const int p0 = (wv_id * 6 + g) * 16;
    const int p = p0 + lm;
    const int e = elist[p];
    const int sn = snd[e], rc = rcv[e];
    const float vx = pos[rc * 3 + 0] - pos[sn * 3 + 0] + shifts[e * 3 + 0];
    const float vy = pos[rc * 3 + 1] - pos[sn * 3 + 1] + shifts[e * 3 + 1];
    const float vz = pos[rc * 3 + 2] - pos[sn * 3 + 2] + shifts[e * 3 + 2];
    const float len = __builtin_amdgcn_sqrtf(vx * vx + vy * vy + vz * vz + 1e-18f);
    const float u = len * 0.2f;  // / R_MAX
    float fc = 0.f;
    if (u < 1.0f) {
      const float u2 = u * u, u5 = u2 * u2 * u;
      fc = 1.0f - 21.0f * u5 + 35.0f * u5 * u - 15.0f * u5 * u2;
    }
    const float pref = 0.6324555320336759f * fc * __builtin_amdgcn_rcpf(fmaxf(len, 1e-9f));
    float ef[8];
#pragma unroll
    for (int k = 0; k < 8; ++k) {
      const float pin = 3.14159274f * (float)(k + 1);
      ef[k] = pref * __sinf(pin * u);
    }

    if (writeY) {
      const float il = __builtin_amdgcn_rcpf(len);
      const float x = vx * il, y = vy * il, z = vz * il;
      const float x2 = x * x, y2 = y * y, z2 = z * z;
      const float s3 = 1.7320508075688772f;
      const float s15 = 3.872983346207417f;
      const float s5h = 1.118033988749895f;
      const float s35_8 = 2.091650066335189f;
      const float s105 = 10.246950765959598f;
      const float s21_8 = 1.6201851746019651f;
      const float s7h = 1.3228756555322954f;
      const float s105h = 5.123475382979799f;
      float4 yq = make_float4(1.f, s3 * x, s3 * y, s3 * z);
      if (grp == 1)
        yq = make_float4(s15 * x * y, s15 * y * z, s5h * (3.f * z2 - 1.f), s15 * x * z);
      if (grp == 2)
        yq = make_float4(0.5f * s15 * (x2 - y2), s35_8 * y * (3.f * x2 - y2),
                         s105 * x * y * z, s21_8 * y * (5.f * z2 - 1.f));
      if (grp == 3)
        yq = make_float4(s7h * z * (5.f * z2 - 3.f), s21_8 * x * (5.f * z2 - 1.f),
                         s105h * z * (x2 - y2), s35_8 * x * (x2 - 3.f * y2));
      *(float4*)&Yout[(size_t)p * 16 + grp * 4] = yq;
    }

    // sedge[p][32]: each of the 4 grp-lanes of edge lm writes its 8-col chunk
    {
      const float4 sa = *(const float4*)&scal[(size_t)sn * 32 + grp * 8];
      const float4 sb = *(const float4*)&scal[(size_t)sn * 32 + grp * 8 + 4];
      *(float4*)&sedge[(size_t)p * 32 + grp * 8] = sa;
      *(float4*)&sedge[(size_t)p * 32 + grp * 8 + 4] = sb;
    }

    // ---- layer 1: A-frag straight from ef (grp0 holds k=0..7, rest zero)
    bf16x8 a1hi, a1lo;
#pragma unroll
    for (int j = 0; j < 8; ++j) {
      const float v = (grp == 0) ? ef[j] : 0.f;
      const unsigned hb = __float_as_uint(v) & 0xFFFF0000u;
      a1hi[j] = (short)(hb >> 16);
      a1lo[j] = (short)(__float_as_uint(v - __uint_as_float(hb)) >> 16);
    }
    f32x4 acc[4];
#pragma unroll
    for (int t = 0; t < 4; ++t) {
      f32x4 a = {0.f, 0.f, 0.f, 0.f};
      a = __builtin_amdgcn_mfma_f32_16x16x32_bf16(a1hi, b1hi[t], a, 0, 0, 0);
      a = __builtin_amdgcn_mfma_f32_16x16x32_bf16(a1lo, b1hi[t], a, 0, 0, 0);
      a = __builtin_amdgcn_mfma_f32_16x16x32_bf16(a1hi, b1lo[t], a, 0, 0, 0);
      acc[t] = a;
    }
#pragma unroll
    for (int t = 0; t < 4; ++t)
#pragma unroll
      for (int r = 0; r < 4; ++r) {
        const float v = silu_f(acc[t][r]);
        const unsigned hb = __float_as_uint(v) & 0xFFFF0000u;
        tw[(t * 16 + lm) * 17 + grp * 4 + r] =
            hb | (__float_as_uint(v - __uint_as_float(hb)) >> 16);
      }
    // ---- read A2 (transpose via LDS) and layer 2
    bf16x8 a2h0, a2h1, a2l0, a2l1;
#pragma unroll
    for (int j = 0; j < 8; ++j) {
      const unsigned u0 = tw[(grp * 8 + j) * 17 + lm];
      const unsigned u1 = tw[(32 + grp * 8 + j) * 17 + lm];
      a2h0[j] = (short)(u0 >> 16);
      a2l0[j] = (short)(u0 & 0xFFFFu);
      a2h1[j] = (short)(u1 >> 16);
      a2l1[j] = (short)(u1 & 0xFFFFu);
    }
#pragma unroll
    for (int t = 0; t < 4; ++t) {
      f32x4 a = {0.f, 0.f, 0.f, 0.f};
      a = __builtin_amdgcn_mfma_f32_16x16x32_bf16(a2h0, b2hi[t][0], a, 0, 0, 0);
      a = __builtin_amdgcn_mfma_f32_16x16x32_bf16(a2h1, b2hi[t][1], a, 0, 0, 0);
      a = __builtin_amdgcn_mfma_f32_16x16x32_bf16(a2l0, b2hi[t][0], a, 0, 0, 0);
      a = __builtin_amdgcn_mfma_f32_16x16x32_bf16(a2l1, b2hi[t][1], a, 0, 0, 0);
      a = __builtin_amdgcn_mfma_f32_16x16x32_bf16(a2h0, b2lo[t][0], a, 0, 0, 0);
      a = __builtin_amdgcn_mfma_f32_16x16x32_bf16(a2h1, b2lo[t][1], a, 0, 0, 0);
      acc[t] = a;
    }
#pragma unroll
    for (int t = 0; t < 4; ++t)
#pragma unroll
      for (int r = 0; r < 4; ++r) {
        const float v = silu_f(acc[t][r]);
        const unsigned hb = __float_as_uint(v) & 0xFFFF0000u;
        tw[(t * 16 + lm) * 17 + grp * 4 + r] =
            hb | (__float_as_uint(v - __uint_as_float(hb)) >> 16);
      }
    // ---- read A3 and layer 3
    bf16x8 a3h0, a3h1, a3l0, a3l1;
#pragma unroll
    for (int j = 0; j < 8; ++j) {
      const unsigned u0 = tw[(grp * 8 + j) * 17 + lm];
      const unsigned u1 = tw[(32 + grp * 8 + j) * 17 + lm];
      a3h0[j] = (short)(u0 >> 16);
      a3l0[j] = (short)(u0 & 0xFFFFu);
      a3h1[j] = (short)(u1 >> 16);
      a3l1[j] = (short)(u1 & 0xFFFFu);
    }
#pragma unroll
    for (int t = 0; t < 4; ++t) {
      f32x4 a = {0.f, 0.f, 0.f, 0.f};
      a = __builtin_amdgcn_mfma_f32_16x16x32_bf16(a3h0, b3hi[t][0], a, 0, 0, 0);
      a = __builtin_amdgcn_mfma_f32_16x16x32_bf16(a3h1, b3hi[t][1], a, 0, 0, 0);
      a = __builtin_amdgcn_mfma_f32_16x16x32_bf16(a3l0, b3hi[t][0], a, 0, 0, 0);
      a = __builtin_amdgcn_mfma_f32_16x16x32_bf16(a3l1, b3hi[t][1], a, 0, 0, 0);
      a = __builtin_amdgcn_mfma_f32_16x16x32_bf16(a3h0, b3lo[t][0], a, 0, 0, 0);
      a = __builtin_amdgcn_mfma_f32_16x16x32_bf16(a3h1, b3lo[t][1], a, 0, 0, 0);
      acc[t] = a;
    }
#pragma unroll
    for (int t = 0; t < 4; ++t)
#pragma unroll
      for (int r = 0; r < 4; ++r) {
        const float v = silu_f(acc[t][r]);
        const unsigned hb = __float_as_uint(v) & 0xFFFF0000u;
        tw[(t * 16 + lm) * 17 + grp * 4 + r] =
            hb | (__float_as_uint(v - __uint_as_float(hb)) >> 16);
      }
    // ---- coalesced h3 writeout: lane = (edge eo, quarter q)
    {
      const int eo = lane >> 2, q = lane & 3;
      unsigned short* hrow = h3 + (size_t)(p0 + eo) * 128;
      u16x8 h0, h1, l0v, l1v;
#pragma unroll
      for (int j = 0; j < 8; ++j) {
        const unsigned ua = tw[(q * 16 + j) * 17 + eo];
        const unsigned ub = tw[(q * 16 + 8 + j) * 17 + eo];
        h0[j] = (unsigned short)(ua >> 16);
        l0v[j] = (unsigned short)(ua & 0xFFFFu);
        h1[j] = (unsigned short)(ub >> 16);
        l1v[j] = (unsigned short)(ub & 0xFFFFu);
      }
      *(u16x8*)(hrow + q * 16) = h0;
      *(u16x8*)(hrow + q * 16 + 8) = h1;
      *(u16x8*)(hrow + 64 + q * 16) = l0v;
      *(u16x8*)(hrow + 64 + q * 16 + 8) = l1v;
    }
  }
}

// ---------------- W4 GEMM via MFMA, depth-4 ring pipeline -----------------
// R12 change: launch_bounds(256,2) -> (256,4). VGPR 108 <= 128 budget, so
// codegen unchanged; residency 2 -> 4 blocks/CU, and 1024 blocks = exactly
// one full pass (256 CU x 4). In-flight loads/SIMD = waves x ring depth.
#define MLOAD(K, tix)                                                         \
  {                                                                           \
    const int tic = ((tix) < ntiles) ? (tix) : (ntiles - 1);                  \
    const int2 td = tdesc[tic];                                               \
    M[K] = (unsigned)td.x;                                                    \
    P[K] = td.y;                                                              \
  }

#define DLOAD(K2)                                                             \
  {                                                                           \
    const int p0 = P[K2];                                                     \
    const int lend = (int)((M[K2] >> 20) & 31u);                              \
    const unsigned short* hp = h3 + (size_t)(p0 + lm) * 128 + grp * 8;        \
    A[K2][0] = *(const bf16x8*)(hp);                                          \
    A[K2][1] = *(const bf16x8*)(hp + 32);                                     \
    A[K2][2] = *(const bf16x8*)(hp + 64);                                     \
    A[K2][3] = *(const bf16x8*)(hp + 96);                                     \
    _Pragma("unroll") for (int r = 0; r < 4; ++r) {                           \
      const int rr = grp * 4 + r;                                             \
      const int pr = p0 + rr;                                                 \
      const float yr = Yb[(size_t)pr * 16 + lm];                              \
      const float Yv = ((rr < lend) ? yr : 0.f) * inv12;                      \
      const float4 s4 = *(const float4*)&sedge[(size_t)pr * 32 + cg * 4];     \
      YS[K2][r][0] = Yv * s4.x;                                               \
      YS[K2][r][1] = Yv * s4.y;                                               \
      YS[K2][r][2] = Yv * s4.z;                                               \
      YS[K2][r][3] = Yv * s4.w;                                               \
    }                                                                         \
  }

#define STEP(K)                                                               \
  {                                                                           \
    const unsigned mcur = M[K];                                               \
    MLOAD(K, tb + 4);                                                         \
    DLOAD((K + 2) & 3);                                                       \
    const int node = (int)(mcur & 0x3FFFu);                                   \
    const bool multi = (mcur & 0x80000000u) != 0u;                            \
    float outv[4];                                                            \
    _Pragma("unroll") for (int t = 0; t < 4; ++t) {                           \
      f32x4 acc = {0.f, 0.f, 0.f, 0.f};                                       \
      acc = __builtin_amdgcn_mfma_f32_16x16x32_bf16(A[K][0], bhi[t][0], acc, 0, 0, 0); \
      acc = __builtin_amdgcn_mfma_f32_16x16x32_bf16(A[K][1], bhi[t][1], acc, 0, 0, 0); \
      acc = __builtin_amdgcn_mfma_f32_16x16x32_bf16(A[K][2], bhi[t][0], acc, 0, 0, 0); \
      acc = __builtin_amdgcn_mfma_f32_16x16x32_bf16(A[K][3], bhi[t][1], acc, 0, 0, 0); \
      acc = __builtin_amdgcn_mfma_f32_16x16x32_bf16(A[K][0], blo[t][0], acc, 0, 0, 0); \
      acc = __builtin_amdgcn_mfma_f32_16x16x32_bf16(A[K][1], blo[t][1], acc, 0, 0, 0); \
      float cp = acc[0] * YS[K][0][t];                                        \
      cp = fmaf(acc[1], YS[K][1][t], cp);                                     \
      cp = fmaf(acc[2], YS[K][2][t], cp);                                     \
      cp = fmaf(acc[3], YS[K][3][t], cp);                                     \
      cp += __shfl_xor(cp, 16);                                               \
      cp += __shfl_xor(cp, 32);                                               \
      outv[t] = cp;                                                           \
    }                                                                         \
    float sel = outv[0];                                                      \
    sel = (grp == 1) ? outv[1] : sel;                                         \
    sel = (grp == 2) ? outv[2] : sel;                                         \
    sel = (grp == 3) ? outv[3] : sel;                                         \
    if (tb < ntiles) {                                                        \
      float* ap = &agg[(size_t)node * 512 + cg * 64 + grp * 16 + lm];         \
      if (multi)                                                              \
        atomicAdd(ap, sel);                                                   \
      else                                                                    \
        *ap = sel;                                                            \
    }                                                                         \
    ++tb;                                                                     \
  }

__global__ __launch_bounds__(256, 4) void k_gather(
    const unsigned short* __restrict__ h3, const float* __restrict__ W4g,
    const float* __restrict__ Yb, const float* __restrict__ sedge,
    const int2* __restrict__ tdesc, const int* __restrict__ ntiles_ptr,
    float* __restrict__ agg) {
  const int bid = blockIdx.x;
  const int xcd = bid & 7, q = bid >> 3, half = q & 1;
  const int s = ((q >> 1) << 3) | xcd;          // stream 0..511
  const int w = threadIdx.x >> 6, lane = threadIdx.x & 63;
  const int grp = lane >> 4, lm = lane & 15;
  const int cg = half * 4 + w;                  // col group 0..7 (64 cols)
  const float inv12 = 1.0f / 12.0f;

  bf16x8 bhi[4][2], blo[4][2];
#pragma unroll
  for (int t = 0; t < 4; ++t) {
    const int col = cg * 64 + t * 16 + lm;
#pragma unroll
    for (int kk = 0; kk < 2; ++kk) {
#pragma unroll
      for (int j = 0; j < 8; ++j) {
        const float wv = W4g[(kk * 32 + grp * 8 + j) * 512 + col];
        const unsigned hb = __float_as_uint(wv) & 0xFFFF0000u;
        bhi[t][kk][j] = (short)(hb >> 16);
        blo[t][kk][j] = (short)(__float_as_uint(wv - __uint_as_float(hb)) >> 16);
      }
    }
  }

  const int ntiles = *ntiles_ptr;
  const int chunk4 = ((((ntiles + 511) >> 9) + 3) & ~3);
  int tb = s * chunk4;

  bf16x8 A[4][4];
  float YS[4][4][4];
  unsigned M[4];
  int P[4];

  MLOAD(0, tb + 0);
  MLOAD(1, tb + 1);
  MLOAD(2, tb + 2);
  MLOAD(3, tb + 3);
  DLOAD(0);
  DLOAD(1);

  for (int jj = 0; jj < chunk4; jj += 4) {
    STEP(0);
    STEP(1);
    STEP(2);
    STEP(3);
  }
}

// ---------------- per-node: Wlin, quadratic, Wprod + skip, desc out -------
__global__ __launch_bounds__(256) void k_node(
    const float* __restrict__ agg, float* __restrict__ nf,
    const float* __restrict__ Wlin, const float* __restrict__ Wprod,
    const float* __restrict__ Wskip, const float* __restrict__ w2v,
    const float* __restrict__ w3v, const int* __restrict__ elem,
    float* __restrict__ scal_out, float* __restrict__ dout, const int layer) {
  __shared__ __align__(16) float aggs[8][512];
  __shared__ __align__(16) float nfs[8][512];
  __shared__ float bs[8][544];  // pitch 17 per channel row
  const int tid = threadIdx.x;
  const int n0 = blockIdx.x * 8;
  for (int i = tid; i < 1024; i += 256) {
    const int nl = i >> 7, qq = i & 127;
    ((f32x4*)aggs)[i] = ((const f32x4*)agg)[(size_t)(n0 + nl) * 128 + qq];
    ((f32x4*)nfs)[i] = ((const f32x4*)nf)[(size_t)(n0 + nl) * 128 + qq];
  }
  __syncthreads();
  const int nl = tid >> 5, o = tid & 31;
  const int n = n0 + nl;
  constexpr int SLa[4] = {0, 1, 4, 9};
  constexpr int ELa[4] = {1, 4, 9, 16};
  float a[16];
#pragma unroll
  for (int m = 0; m < 16; ++m) a[m] = 0.f;
#pragma unroll
  for (int l = 0; l < 4; ++l) {
    for (int c = 0; c < 32; ++c) {
      const float w = Wlin[(l * 32 + c) * 32 + o];
#pragma unroll
      for (int m = SLa[l]; m < ELa[l]; ++m) a[m] = fmaf(aggs[nl][c * 16 + m], w, a[m]);
    }
  }
  const float inv = a[0];
  float p2 = 0.f;
#pragma unroll
  for (int m = 0; m < 16; ++m) p2 = fmaf(a[m], a[m], p2);
  a[0] = inv + w2v[o] * p2 + w3v[o] * inv * p2;
#pragma unroll
  for (int m = 0; m < 16; ++m) bs[nl][o * 17 + m] = a[m];
  __syncthreads();
  float outv[16];
#pragma unroll
  for (int m = 0; m < 16; ++m) outv[m] = 0.f;
#pragma unroll
  for (int l = 0; l < 4; ++l) {
    for (int c = 0; c < 32; ++c) {
      const float w = Wprod[(l * 32 + c) * 32 + o];
#pragma unroll
      for (int m = SLa[l]; m < ELa[l]; ++m) outv[m] = fmaf(bs[nl][c * 17 + m], w, outv[m]);
    }
  }
  const int z = elem[n];
  const float* wsk = Wskip + z * 1024;
  for (int c = 0; c < 32; ++c) {
    const float w = wsk[c * 32 + o];
#pragma unroll
    for (int m = 0; m < 16; ++m) outv[m] = fmaf(nfs[nl][c * 16 + m], w, outv[m]);
  }
  float* op = nf + (size_t)n * 512 + o * 16;
  *(float4*)&op[0] = make_float4(outv[0], outv[1], outv[2], outv[3]);
  *(float4*)&op[4] = make_float4(outv[4], outv[5], outv[6], outv[7]);
  *(float4*)&op[8] = make_float4(outv[8], outv[9], outv[10], outv[11]);
  *(float4*)&op[12] = make_float4(outv[12], outv[13], outv[14], outv[15]);
  scal_out[n * 32 + o] = outv[0];
  dout[(size_t)n * 64 + layer * 32 + o] = outv[0];
}

extern "C" void kernel_launch(void* const* d_in, const int* in_sizes, int n_in,
                              void* d_out, int out_size, void* d_ws, size_t ws_size,
                              hipStream_t stream) {
  const float* pos = (const float*)d_in[0];
  const float* attrs = (const float*)d_in[1];
  const float* shifts = (const float*)d_in[2];
  const int* eidx = (const int*)d_in[3];
  const float* W_embed = (const float*)d_in[4];
  const float* W1 = (const float*)d_in[5];
  const float* W2 = (const float*)d_in[6];
  const float* W3 = (const float*)d_in[7];
  const float* W4 = (const float*)d_in[8];
  const float* Wlin = (const float*)d_in[9];
  const float* Wskip = (const float*)d_in[10];
  const float* w2v = (const float*)d_in[11];
  const float* w3v = (const float*)d_in[12];
  const float* Wprod = (const float*)d_in[13];
  float* out = (float*)d_out;
  const int* snd = eidx;
  const int* rcv = eidx + N_EDGES_C;

  char* p = (char*)d_ws;
  auto take = [&](size_t bytes) {
    char* q = p;
    p += (bytes + 255) & ~(size_t)255;
    return q;
  };
  int* counts = (int*)take((size_t)N_NODES_C * 4);
  int* row_start = (int*)take((size_t)(N_NODES_C + 1) * 4);
  int* cursor = (int*)take((size_t)N_NODES_C * 4);
  int* tstart = (int*)take((size_t)(N_NODES_C + 1) * 4);
  int* elist = (int*)take((size_t)N_EDGES_C * 4);
  int2* tdesc = (int2*)take((size_t)MAX_TILES * 8);
  int* elem = (int*)take((size_t)N_NODES_C * 4);
  float* Ybuf = (float*)take((size_t)(N_EDGES_C + 16) * 16 * 4);
  unsigned short* h3 = (unsigned short*)take((size_t)(N_EDGES_C + 16) * 128 * 2);
  float* sedge = (float*)take((size_t)(N_EDGES_C + 16) * 32 * 4);
  float* agg = (float*)take((size_t)N_NODES_C * 512 * 4);
  float* nf = (float*)take((size_t)N_NODES_C * 512 * 4);
  float* scal0 = (float*)take((size_t)N_NODES_C * 32 * 4);
  float* scal1 = (float*)take((size_t)N_NODES_C * 32 * 4);
  (void)ws_size; (void)in_sizes; (void)n_in; (void)out_size;

  hipMemsetAsync(counts, 0, (size_t)N_NODES_C * 4, stream);
  k_count<<<N_EDGES_C / 256, 256, 0, stream>>>(rcv, counts);
  k_scan<<<1, 1024, 0, stream>>>(counts, row_start, cursor, tstart);
  k_fill<<<N_EDGES_C / 256, 256, 0, stream>>>(rcv, cursor, elist);
  k_tiles<<<N_NODES_C / 256, 256, 0, stream>>>(row_start, tstart, tdesc);
  k_elem<<<N_NODES_C / 256, 256, 0, stream>>>(attrs, elem);
  k_embed<<<N_NODES_C * 32 / 256, 256, 0, stream>>>(attrs, W_embed, scal0, nf);

  for (int i = 0; i < 2; ++i) {
    k_radial<<<512, 256, 0, stream>>>(pos, shifts, snd, rcv, elist,
                                      i == 0 ? scal0 : scal1,
                                      W1 + (size_t)i * 8 * 64, W2 + (size_t)i * 64 * 64,
                                      W3 + (size_t)i * 64 * 64, h3, sedge, Ybuf,
                                      i == 0 ? 1 : 0);
    hipMemsetAsync(agg, 0, (size_t)N_NODES_C * 512 * 4, stream);
    k_gather<<<1024, 256, 0, stream>>>(h3, W4 + (size_t)i * 64 * 512, Ybuf, sedge,
                                       tdesc, tstart + N_NODES_C, agg);
    k_node<<<N_NODES_C / 8, 256, 0, stream>>>(agg, nf, Wlin + (size_t)i * 4096,
                                              Wprod + (size_t)i * 4096,
                                              Wskip + (size_t)i * 8192,
                                              w2v + (size_t)i * 32, w3v + (size_t)i * 32,
                                              elem, scal1, out, i);
  }
}

// Round 13
// 711.440 us; speedup vs baseline: 1.1398x; 1.1398x over previous
//
#include <hip/hip_runtime.h>
#include <math.h>

#define N_NODES_C 16384
#define N_EDGES_C 196608
#define MAX_TILES 32768

typedef short bf16x8 __attribute__((ext_vector_type(8)));
typedef unsigned short u16x8 __attribute__((ext_vector_type(8)));
typedef float f32x4 __attribute__((ext_vector_type(4)));
typedef float f32x8 __attribute__((ext_vector_type(8)));

__device__ __forceinline__ float silu_f(float x) {
  return x * __builtin_amdgcn_rcpf(1.0f + __expf(-x));
}

// ---------------- CSR build ----------------
__global__ void k_count(const int* __restrict__ rcv, int* __restrict__ counts) {
  int e = blockIdx.x * 256 + threadIdx.x;
  atomicAdd(&counts[rcv[e]], 1);
}

// dual prefix sum: exact CSR offsets AND tile offsets (ceil(cnt/16))
__global__ __launch_bounds__(1024) void k_scan(const int* __restrict__ counts,
                                               int* __restrict__ row_start,
                                               int* __restrict__ cursor,
                                               int* __restrict__ tstart) {
  __shared__ int s1a[1024];
  __shared__ int s2a[1024];
  const int tid = threadIdx.x;
  int loc[16];
  int s1 = 0, s2 = 0;
#pragma unroll
  for (int i = 0; i < 16; ++i) {
    loc[i] = counts[tid * 16 + i];
    s1 += loc[i];
    s2 += (loc[i] + 15) >> 4;
  }
  s1a[tid] = s1;
  s2a[tid] = s2;
  __syncthreads();
  for (int off = 1; off < 1024; off <<= 1) {
    int t1 = (tid >= off) ? s1a[tid - off] : 0;
    int t2 = (tid >= off) ? s2a[tid - off] : 0;
    __syncthreads();
    s1a[tid] += t1;
    s2a[tid] += t2;
    __syncthreads();
  }
  int e1 = s1a[tid] - s1, e2 = s2a[tid] - s2;
#pragma unroll
  for (int i = 0; i < 16; ++i) {
    row_start[tid * 16 + i] = e1;
    cursor[tid * 16 + i] = e1;
    tstart[tid * 16 + i] = e2;
    e1 += loc[i];
    e2 += (loc[i] + 15) >> 4;
  }
  if (tid == 1023) {
    row_start[N_NODES_C] = e1;
    tstart[N_NODES_C] = e2;
  }
}

__global__ void k_fill(const int* __restrict__ rcv, int* __restrict__ cursor,
                       int* __restrict__ elist) {
  int e = blockIdx.x * 256 + threadIdx.x;
  int slot = atomicAdd(&cursor[rcv[e]], 1);
  elist[slot] = e;
}

// tile descriptors: x = node | len<<20 | multi<<31 ; y = p0 (CSR offset)
__global__ void k_tiles(const int* __restrict__ row_start, const int* __restrict__ tstart,
                        int2* __restrict__ tdesc) {
  const int n = blockIdx.x * 256 + threadIdx.x;
  const int e0 = row_start[n], e1 = row_start[n + 1];
  const int cnt = e1 - e0;
  const int nt = (cnt + 15) >> 4;
  const int t0 = tstart[n];
  const unsigned mbit = (nt > 1) ? 0x80000000u : 0u;
  for (int j = 0; j < nt; ++j) {
    int len = cnt - 16 * j;
    if (len > 16) len = 16;
    tdesc[t0 + j] = make_int2((int)((unsigned)n | ((unsigned)len << 20) | mbit), e0 + 16 * j);
  }
}

// ---------------- node element id + embedding ----------------
__global__ void k_elem(const float* __restrict__ attrs, int* __restrict__ elem) {
  int n = blockIdx.x * 256 + threadIdx.x;
  const float* a = attrs + n * 8;
  int best = 0;
  float bv = a[0];
#pragma unroll
  for (int z = 1; z < 8; ++z) {
    if (a[z] > bv) { bv = a[z]; best = z; }
  }
  elem[n] = best;
}

__global__ void k_embed(const float* __restrict__ attrs, const float* __restrict__ Wemb,
                        float* __restrict__ scal0, float* __restrict__ nf) {
  int gid = blockIdx.x * 256 + threadIdx.x;  // N*32 threads
  int n = gid >> 5, c = gid & 31;
  float s = 0.f;
#pragma unroll
  for (int z = 0; z < 8; ++z) s = fmaf(attrs[n * 8 + z], Wemb[z * 32 + c], s);
  scal0[gid] = s;
  float* row = nf + (size_t)n * 512 + c * 16;
  *(float4*)&row[0] = make_float4(s, 0.f, 0.f, 0.f);
  *(float4*)&row[4] = make_float4(0.f, 0.f, 0.f, 0.f);
  *(float4*)&row[8] = make_float4(0.f, 0.f, 0.f, 0.f);
  *(float4*)&row[12] = make_float4(0.f, 0.f, 0.f, 0.f);
}

// ---------------- per-edge radial MLP via MFMA (+SH, +s-edge) -------------
// Wave = 16 edges (one MFMA M-tile), 6 groups per wave, barrier-free.
__global__ __launch_bounds__(256, 2) void k_radial(
    const float* __restrict__ pos, const float* __restrict__ shifts,
    const int* __restrict__ snd, const int* __restrict__ rcv,
    const int* __restrict__ elist, const float* __restrict__ scal,
    const float* __restrict__ W1g, const float* __restrict__ W2g,
    const float* __restrict__ W3g, unsigned short* __restrict__ h3,
    float* __restrict__ sedge, float* __restrict__ Yout, const int writeY) {
  __shared__ unsigned tb[4][64 * 17];
  const int wid = threadIdx.x >> 6, lane = threadIdx.x & 63;
  const int grp = lane >> 4, lm = lane & 15;
  unsigned* tw = tb[wid];

  // ---- weight B-fragments (hi/lo bf16), loaded once per wave ----
  bf16x8 b1hi[4], b1lo[4];
#pragma unroll
  for (int t = 0; t < 4; ++t) {
#pragma unroll
    for (int j = 0; j < 8; ++j) {
      const float wv = (grp == 0) ? W1g[j * 64 + t * 16 + lm] : 0.f;
      const unsigned hb = __float_as_uint(wv) & 0xFFFF0000u;
      b1hi[t][j] = (short)(hb >> 16);
      b1lo[t][j] = (short)(__float_as_uint(wv - __uint_as_float(hb)) >> 16);
    }
  }
  bf16x8 b2hi[4][2], b2lo[4][2], b3hi[4][2], b3lo[4][2];
#pragma unroll
  for (int t = 0; t < 4; ++t) {
#pragma unroll
    for (int kf = 0; kf < 2; ++kf) {
#pragma unroll
      for (int j = 0; j < 8; ++j) {
        const int widx = (kf * 32 + grp * 8 + j) * 64 + t * 16 + lm;
        {
          const float wv = W2g[widx];
          const unsigned hb = __float_as_uint(wv) & 0xFFFF0000u;
          b2hi[t][kf][j] = (short)(hb >> 16);
          b2lo[t][kf][j] = (short)(__float_as_uint(wv - __uint_as_float(hb)) >> 16);
        }
        {
          const float wv = W3g[widx];
          const unsigned hb = __float_as_uint(wv) & 0xFFFF0000u;
          b3hi[t][kf][j] = (short)(hb >> 16);
          b3lo[t][kf][j] = (short)(__float_as_uint(wv - __uint_as_float(hb)) >> 16);
        }
      }
    }
  }

  const int wv_id = blockIdx.x * 4 + wid;  // 0..2047
  for (int g = 0; g < 6; ++g) {
    const int p0 = (wv_id * 6 + g) * 16;
    const int p = p0 + lm;
    const int e = elist[p];
    const int sn = snd[e], rc = rcv[e];
    const float vx = pos[rc * 3 + 0] - pos[sn * 3 + 0] + shifts[e * 3 + 0];
    const float vy = pos[rc * 3 + 1] - pos[sn * 3 + 1] + shifts[e * 3 + 1];
    const float vz = pos[rc * 3 + 2] - pos[sn * 3 + 2] + shifts[e * 3 + 2];
    const float len = __builtin_amdgcn_sqrtf(vx * vx + vy * vy + vz * vz + 1e-18f);
    const float u = len * 0.2f;  // / R_MAX
    float fc = 0.f;
    if (u < 1.0f) {
      const float u2 = u * u, u5 = u2 * u2 * u;
      fc = 1.0f - 21.0f * u5 + 35.0f * u5 * u - 15.0f * u5 * u2;
    }
    const float pref = 0.6324555320336759f * fc * __builtin_amdgcn_rcpf(fmaxf(len, 1e-9f));
    float ef[8];
#pragma unroll
    for (int k = 0; k < 8; ++k) {
      const float pin = 3.14159274f * (float)(k + 1);
      ef[k] = pref * __sinf(pin * u);
    }

    if (writeY) {
      const float il = __builtin_amdgcn_rcpf(len);
      const float x = vx * il, y = vy * il, z = vz * il;
      const float x2 = x * x, y2 = y * y, z2 = z * z;
      const float s3 = 1.7320508075688772f;
      const float s15 = 3.872983346207417f;
      const float s5h = 1.118033988749895f;
      const float s35_8 = 2.091650066335189f;
      const float s105 = 10.246950765959598f;
      const float s21_8 = 1.6201851746019651f;
      const float s7h = 1.3228756555322954f;
      const float s105h = 5.123475382979799f;
      float4 yq = make_float4(1.f, s3 * x, s3 * y, s3 * z);
      if (grp == 1)
        yq = make_float4(s15 * x * y, s15 * y * z, s5h * (3.f * z2 - 1.f), s15 * x * z);
      if (grp == 2)
        yq = make_float4(0.5f * s15 * (x2 - y2), s35_8 * y * (3.f * x2 - y2),
                         s105 * x * y * z, s21_8 * y * (5.f * z2 - 1.f));
      if (grp == 3)
        yq = make_float4(s7h * z * (5.f * z2 - 3.f), s21_8 * x * (5.f * z2 - 1.f),
                         s105h * z * (x2 - y2), s35_8 * x * (x2 - 3.f * y2));
      *(float4*)&Yout[(size_t)p * 16 + grp * 4] = yq;
    }

    // sedge[p][32]: each of the 4 grp-lanes of edge lm writes its 8-col chunk
    {
      const float4 sa = *(const float4*)&scal[(size_t)sn * 32 + grp * 8];
      const float4 sb = *(const float4*)&scal[(size_t)sn * 32 + grp * 8 + 4];
      *(float4*)&sedge[(size_t)p * 32 + grp * 8] = sa;
      *(float4*)&sedge[(size_t)p * 32 + grp * 8 + 4] = sb;
    }

    // ---- layer 1: A-frag straight from ef (grp0 holds k=0..7, rest zero)
    bf16x8 a1hi, a1lo;
#pragma unroll
    for (int j = 0; j < 8; ++j) {
      const float v = (grp == 0) ? ef[j] : 0.f;
      const unsigned hb = __float_as_uint(v) & 0xFFFF0000u;
      a1hi[j] = (short)(hb >> 16);
      a1lo[j] = (short)(__float_as_uint(v - __uint_as_float(hb)) >> 16);
    }
    f32x4 acc[4];
#pragma unroll
    for (int t = 0; t < 4; ++t) {
      f32x4 a = {0.f, 0.f, 0.f, 0.f};
      a = __builtin_amdgcn_mfma_f32_16x16x32_bf16(a1hi, b1hi[t], a, 0, 0, 0);
      a = __builtin_amdgcn_mfma_f32_16x16x32_bf16(a1lo, b1hi[t], a, 0, 0, 0);
      a = __builtin_amdgcn_mfma_f32_16x16x32_bf16(a1hi, b1lo[t], a, 0, 0, 0);
      acc[t] = a;
    }
#pragma unroll
    for (int t = 0; t < 4; ++t)
#pragma unroll
      for (int r = 0; r < 4; ++r) {
        const float v = silu_f(acc[t][r]);
        const unsigned hb = __float_as_uint(v) & 0xFFFF0000u;
        tw[(t * 16 + lm) * 17 + grp * 4 + r] =
            hb | (__float_as_uint(v - __uint_as_float(hb)) >> 16);
      }
    // ---- read A2 (transpose via LDS) and layer 2
    bf16x8 a2h0, a2h1, a2l0, a2l1;
#pragma unroll
    for (int j = 0; j < 8; ++j) {
      const unsigned u0 = tw[(grp * 8 + j) * 17 + lm];
      const unsigned u1 = tw[(32 + grp * 8 + j) * 17 + lm];
      a2h0[j] = (short)(u0 >> 16);
      a2l0[j] = (short)(u0 & 0xFFFFu);
      a2h1[j] = (short)(u1 >> 16);
      a2l1[j] = (short)(u1 & 0xFFFFu);
    }
#pragma unroll
    for (int t = 0; t < 4; ++t) {
      f32x4 a = {0.f, 0.f, 0.f, 0.f};
      a = __builtin_amdgcn_mfma_f32_16x16x32_bf16(a2h0, b2hi[t][0], a, 0, 0, 0);
      a = __builtin_amdgcn_mfma_f32_16x16x32_bf16(a2h1, b2hi[t][1], a, 0, 0, 0);
      a = __builtin_amdgcn_mfma_f32_16x16x32_bf16(a2l0, b2hi[t][0], a, 0, 0, 0);
      a = __builtin_amdgcn_mfma_f32_16x16x32_bf16(a2l1, b2hi[t][1], a, 0, 0, 0);
      a = __builtin_amdgcn_mfma_f32_16x16x32_bf16(a2h0, b2lo[t][0], a, 0, 0, 0);
      a = __builtin_amdgcn_mfma_f32_16x16x32_bf16(a2h1, b2lo[t][1], a, 0, 0, 0);
      acc[t] = a;
    }
#pragma unroll
    for (int t = 0; t < 4; ++t)
#pragma unroll
      for (int r = 0; r < 4; ++r) {
        const float v = silu_f(acc[t][r]);
        const unsigned hb = __float_as_uint(v) & 0xFFFF0000u;
        tw[(t * 16 + lm) * 17 + grp * 4 + r] =
            hb | (__float_as_uint(v - __uint_as_float(hb)) >> 16);
      }
    // ---- read A3 and layer 3
    bf16x8 a3h0, a3h1, a3l0, a3l1;
#pragma unroll
    for (int j = 0; j < 8; ++j) {
      const unsigned u0 = tw[(grp * 8 + j) * 17 + lm];
      const unsigned u1 = tw[(32 + grp * 8 + j) * 17 + lm];
      a3h0[j] = (short)(u0 >> 16);
      a3l0[j] = (short)(u0 & 0xFFFFu);
      a3h1[j] = (short)(u1 >> 16);
      a3l1[j] = (short)(u1 & 0xFFFFu);
    }
#pragma unroll
    for (int t = 0; t < 4; ++t) {
      f32x4 a = {0.f, 0.f, 0.f, 0.f};
      a = __builtin_amdgcn_mfma_f32_16x16x32_bf16(a3h0, b3hi[t][0], a, 0, 0, 0);
      a = __builtin_amdgcn_mfma_f32_16x16x32_bf16(a3h1, b3hi[t][1], a, 0, 0, 0);
      a = __builtin_amdgcn_mfma_f32_16x16x32_bf16(a3l0, b3hi[t][0], a, 0, 0, 0);
      a = __builtin_amdgcn_mfma_f32_16x16x32_bf16(a3l1, b3hi[t][1], a, 0, 0, 0);
      a = __builtin_amdgcn_mfma_f32_16x16x32_bf16(a3h0, b3lo[t][0], a, 0, 0, 0);
      a = __builtin_amdgcn_mfma_f32_16x16x32_bf16(a3h1, b3lo[t][1], a, 0, 0, 0);
      acc[t] = a;
    }
#pragma unroll
    for (int t = 0; t < 4; ++t)
#pragma unroll
      for (int r = 0; r < 4; ++r) {
        const float v = silu_f(acc[t][r]);
        const unsigned hb = __float_as_uint(v) & 0xFFFF0000u;
        tw[(t * 16 + lm) * 17 + grp * 4 + r] =
            hb | (__float_as_uint(v - __uint_as_float(hb)) >> 16);
      }
    // ---- coalesced h3 writeout: lane = (edge eo, quarter q)
    {
      const int eo = lane >> 2, q = lane & 3;
      unsigned short* hrow = h3 + (size_t)(p0 + eo) * 128;
      u16x8 h0, h1, l0v, l1v;
#pragma unroll
      for (int j = 0; j < 8; ++j) {
        const unsigned ua = tw[(q * 16 + j) * 17 + eo];
        const unsigned ub = tw[(q * 16 + 8 + j) * 17 + eo];
        h0[j] = (unsigned short)(ua >> 16);
        l0v[j] = (unsigned short)(ua & 0xFFFFu);
        h1[j] = (unsigned short)(ub >> 16);
        l1v[j] = (unsigned short)(ub & 0xFFFFu);
      }
      *(u16x8*)(hrow + q * 16) = h0;
      *(u16x8*)(hrow + q * 16 + 8) = h1;
      *(u16x8*)(hrow + 64 + q * 16) = l0v;
      *(u16x8*)(hrow + 64 + q * 16 + 8) = l1v;
    }
  }
}

// ---------------- W4 GEMM via MFMA, depth-4 ring pipeline -----------------
// R13: launch_bounds(256,3) — budget ~170 regs: ring's 108 VGPR + AGPRs fit
// WITHOUT squeeze (R12's (256,4) = 128 budget caused spill: VGPR 108->64,
// FETCH 47->792 MB, 3x slower). Grid 768 = 256 CU x 3 -> one full pass,
// 384 XCD-paired streams.
#define MLOAD(K, tix)                                                         \
  {                                                                           \
    const int tic = ((tix) < ntiles) ? (tix) : (ntiles - 1);                  \
    const int2 td = tdesc[tic];                                               \
    M[K] = (unsigned)td.x;                                                    \
    P[K] = td.y;                                                              \
  }

#define DLOAD(K2)                                                             \
  {                                                                           \
    const int p0 = P[K2];                                                     \
    const int lend = (int)((M[K2] >> 20) & 31u);                              \
    const unsigned short* hp = h3 + (size_t)(p0 + lm) * 128 + grp * 8;        \
    A[K2][0] = *(const bf16x8*)(hp);                                          \
    A[K2][1] = *(const bf16x8*)(hp + 32);                                     \
    A[K2][2] = *(const bf16x8*)(hp + 64);                                     \
    A[K2][3] = *(const bf16x8*)(hp + 96);                                     \
    _Pragma("unroll") for (int r = 0; r < 4; ++r) {                           \
      const int rr = grp * 4 + r;                                             \
      const int pr = p0 + rr;                                                 \
      const float yr = Yb[(size_t)pr * 16 + lm];                              \
      const float Yv = ((rr < lend) ? yr : 0.f) * inv12;                      \
      const float4 s4 = *(const float4*)&sedge[(size_t)pr * 32 + cg * 4];     \
      YS[K2][r][0] = Yv * s4.x;                                               \
      YS[K2][r][1] = Yv * s4.y;                                               \
      YS[K2][r][2] = Yv * s4.z;                                               \
      YS[K2][r][3] = Yv * s4.w;                                               \
    }                                                                         \
  }

#define STEP(K)                                                               \
  {                                                                           \
    const unsigned mcur = M[K];                                               \
    MLOAD(K, tb + 4);                                                         \
    DLOAD((K + 2) & 3);                                                       \
    const int node = (int)(mcur & 0x3FFFu);                                   \
    const bool multi = (mcur & 0x80000000u) != 0u;                            \
    float outv[4];                                                            \
    _Pragma("unroll") for (int t = 0; t < 4; ++t) {                           \
      f32x4 acc = {0.f, 0.f, 0.f, 0.f};                                       \
      acc = __builtin_amdgcn_mfma_f32_16x16x32_bf16(A[K][0], bhi[t][0], acc, 0, 0, 0); \
      acc = __builtin_amdgcn_mfma_f32_16x16x32_bf16(A[K][1], bhi[t][1], acc, 0, 0, 0); \
      acc = __builtin_amdgcn_mfma_f32_16x16x32_bf16(A[K][2], bhi[t][0], acc, 0, 0, 0); \
      acc = __builtin_amdgcn_mfma_f32_16x16x32_bf16(A[K][3], bhi[t][1], acc, 0, 0, 0); \
      acc = __builtin_amdgcn_mfma_f32_16x16x32_bf16(A[K][0], blo[t][0], acc, 0, 0, 0); \
      acc = __builtin_amdgcn_mfma_f32_16x16x32_bf16(A[K][1], blo[t][1], acc, 0, 0, 0); \
      float cp = acc[0] * YS[K][0][t];                                        \
      cp = fmaf(acc[1], YS[K][1][t], cp);                                     \
      cp = fmaf(acc[2], YS[K][2][t], cp);                                     \
      cp = fmaf(acc[3], YS[K][3][t], cp);                                     \
      cp += __shfl_xor(cp, 16);                                               \
      cp += __shfl_xor(cp, 32);                                               \
      outv[t] = cp;                                                           \
    }                                                                         \
    float sel = outv[0];                                                      \
    sel = (grp == 1) ? outv[1] : sel;                                         \
    sel = (grp == 2) ? outv[2] : sel;                                         \
    sel = (grp == 3) ? outv[3] : sel;                                         \
    if (tb < ntiles) {                                                        \
      float* ap = &agg[(size_t)node * 512 + cg * 64 + grp * 16 + lm];         \
      if (multi)                                                              \
        atomicAdd(ap, sel);                                                   \
      else                                                                    \
        *ap = sel;                                                            \
    }                                                                         \
    ++tb;                                                                     \
  }

__global__ __launch_bounds__(256, 3) void k_gather(
    const unsigned short* __restrict__ h3, const float* __restrict__ W4g,
    const float* __restrict__ Yb, const float* __restrict__ sedge,
    const int2* __restrict__ tdesc, const int* __restrict__ ntiles_ptr,
    float* __restrict__ agg) {
  const int bid = blockIdx.x;
  const int xcd = bid & 7, q = bid >> 3, half = q & 1;
  const int s = ((q >> 1) << 3) | xcd;          // stream 0..383
  const int w = threadIdx.x >> 6, lane = threadIdx.x & 63;
  const int grp = lane >> 4, lm = lane & 15;
  const int cg = half * 4 + w;                  // col group 0..7 (64 cols)
  const float inv12 = 1.0f / 12.0f;

  bf16x8 bhi[4][2], blo[4][2];
#pragma unroll
  for (int t = 0; t < 4; ++t) {
    const int col = cg * 64 + t * 16 + lm;
#pragma unroll
    for (int kk = 0; kk < 2; ++kk) {
#pragma unroll
      for (int j = 0; j < 8; ++j) {
        const float wv = W4g[(kk * 32 + grp * 8 + j) * 512 + col];
        const unsigned hb = __float_as_uint(wv) & 0xFFFF0000u;
        bhi[t][kk][j] = (short)(hb >> 16);
        blo[t][kk][j] = (short)(__float_as_uint(wv - __uint_as_float(hb)) >> 16);
      }
    }
  }

  const int ntiles = *ntiles_ptr;
  const int chunk4 = ((((ntiles + 383) / 384) + 3) & ~3);
  int tb = s * chunk4;

  bf16x8 A[4][4];
  float YS[4][4][4];
  unsigned M[4];
  int P[4];

  MLOAD(0, tb + 0);
  MLOAD(1, tb + 1);
  MLOAD(2, tb + 2);
  MLOAD(3, tb + 3);
  DLOAD(0);
  DLOAD(1);

  for (int jj = 0; jj < chunk4; jj += 4) {
    STEP(0);
    STEP(1);
    STEP(2);
    STEP(3);
  }
}

// ---------------- per-node: Wlin, quadratic, Wprod + skip, desc out -------
__global__ __launch_bounds__(256) void k_node(
    const float* __restrict__ agg, float* __restrict__ nf,
    const float* __restrict__ Wlin, const float* __restrict__ Wprod,
    const float* __restrict__ Wskip, const float* __restrict__ w2v,
    const float* __restrict__ w3v, const int* __restrict__ elem,
    float* __restrict__ scal_out, float* __restrict__ dout, const int layer) {
  __shared__ __align__(16) float aggs[8][512];
  __shared__ __align__(16) float nfs[8][512];
  __shared__ float bs[8][544];  // pitch 17 per channel row
  const int tid = threadIdx.x;
  const int n0 = blockIdx.x * 8;
  for (int i = tid; i < 1024; i += 256) {
    const int nl = i >> 7, qq = i & 127;
    ((f32x4*)aggs)[i] = ((const f32x4*)agg)[(size_t)(n0 + nl) * 128 + qq];
    ((f32x4*)nfs)[i] = ((const f32x4*)nf)[(size_t)(n0 + nl) * 128 + qq];
  }
  __syncthreads();
  const int nl = tid >> 5, o = tid & 31;
  const int n = n0 + nl;
  constexpr int SLa[4] = {0, 1, 4, 9};
  constexpr int ELa[4] = {1, 4, 9, 16};
  float a[16];
#pragma unroll
  for (int m = 0; m < 16; ++m) a[m] = 0.f;
#pragma unroll
  for (int l = 0; l < 4; ++l) {
    for (int c = 0; c < 32; ++c) {
      const float w = Wlin[(l * 32 + c) * 32 + o];
#pragma unroll
      for (int m = SLa[l]; m < ELa[l]; ++m) a[m] = fmaf(aggs[nl][c * 16 + m], w, a[m]);
    }
  }
  const float inv = a[0];
  float p2 = 0.f;
#pragma unroll
  for (int m = 0; m < 16; ++m) p2 = fmaf(a[m], a[m], p2);
  a[0] = inv + w2v[o] * p2 + w3v[o] * inv * p2;
#pragma unroll
  for (int m = 0; m < 16; ++m) bs[nl][o * 17 + m] = a[m];
  __syncthreads();
  float outv[16];
#pragma unroll
  for (int m = 0; m < 16; ++m) outv[m] = 0.f;
#pragma unroll
  for (int l = 0; l < 4; ++l) {
    for (int c = 0; c < 32; ++c) {
      const float w = Wprod[(l * 32 + c) * 32 + o];
#pragma unroll
      for (int m = SLa[l]; m < ELa[l]; ++m) outv[m] = fmaf(bs[nl][c * 17 + m], w, outv[m]);
    }
  }
  const int z = elem[n];
  const float* wsk = Wskip + z * 1024;
  for (int c = 0; c < 32; ++c) {
    const float w = wsk[c * 32 + o];
#pragma unroll
    for (int m = 0; m < 16; ++m) outv[m] = fmaf(nfs[nl][c * 16 + m], w, outv[m]);
  }
  float* op = nf + (size_t)n * 512 + o * 16;
  *(float4*)&op[0] = make_float4(outv[0], outv[1], outv[2], outv[3]);
  *(float4*)&op[4] = make_float4(outv[4], outv[5], outv[6], outv[7]);
  *(float4*)&op[8] = make_float4(outv[8], outv[9], outv[10], outv[11]);
  *(float4*)&op[12] = make_float4(outv[12], outv[13], outv[14], outv[15]);
  scal_out[n * 32 + o] = outv[0];
  dout[(size_t)n * 64 + layer * 32 + o] = outv[0];
}

extern "C" void kernel_launch(void* const* d_in, const int* in_sizes, int n_in,
                              void* d_out, int out_size, void* d_ws, size_t ws_size,
                              hipStream_t stream) {
  const float* pos = (const float*)d_in[0];
  const float* attrs = (const float*)d_in[1];
  const float* shifts = (const float*)d_in[2];
  const int* eidx = (const int*)d_in[3];
  const float* W_embed = (const float*)d_in[4];
  const float* W1 = (const float*)d_in[5];
  const float* W2 = (const float*)d_in[6];
  const float* W3 = (const float*)d_in[7];
  const float* W4 = (const float*)d_in[8];
  const float* Wlin = (const float*)d_in[9];
  const float* Wskip = (const float*)d_in[10];
  const float* w2v = (const float*)d_in[11];
  const float* w3v = (const float*)d_in[12];
  const float* Wprod = (const float*)d_in[13];
  float* out = (float*)d_out;
  const int* snd = eidx;
  const int* rcv = eidx + N_EDGES_C;

  char* p = (char*)d_ws;
  auto take = [&](size_t bytes) {
    char* q = p;
    p += (bytes + 255) & ~(size_t)255;
    return q;
  };
  int* counts = (int*)take((size_t)N_NODES_C * 4);
  int* row_start = (int*)take((size_t)(N_NODES_C + 1) * 4);
  int* cursor = (int*)take((size_t)N_NODES_C * 4);
  int* tstart = (int*)take((size_t)(N_NODES_C + 1) * 4);
  int* elist = (int*)take((size_t)N_EDGES_C * 4);
  int2* tdesc = (int2*)take((size_t)MAX_TILES * 8);
  int* elem = (int*)take((size_t)N_NODES_C * 4);
  float* Ybuf = (float*)take((size_t)(N_EDGES_C + 16) * 16 * 4);
  unsigned short* h3 = (unsigned short*)take((size_t)(N_EDGES_C + 16) * 128 * 2);
  float* sedge = (float*)take((size_t)(N_EDGES_C + 16) * 32 * 4);
  float* agg = (float*)take((size_t)N_NODES_C * 512 * 4);
  float* nf = (float*)take((size_t)N_NODES_C * 512 * 4);
  float* scal0 = (float*)take((size_t)N_NODES_C * 32 * 4);
  float* scal1 = (float*)take((size_t)N_NODES_C * 32 * 4);
  (void)ws_size; (void)in_sizes; (void)n_in; (void)out_size;

  hipMemsetAsync(counts, 0, (size_t)N_NODES_C * 4, stream);
  k_count<<<N_EDGES_C / 256, 256, 0, stream>>>(rcv, counts);
  k_scan<<<1, 1024, 0, stream>>>(counts, row_start, cursor, tstart);
  k_fill<<<N_EDGES_C / 256, 256, 0, stream>>>(rcv, cursor, elist);
  k_tiles<<<N_NODES_C / 256, 256, 0, stream>>>(row_start, tstart, tdesc);
  k_elem<<<N_NODES_C / 256, 256, 0, stream>>>(attrs, elem);
  k_embed<<<N_NODES_C * 32 / 256, 256, 0, stream>>>(attrs, W_embed, scal0, nf);

  for (int i = 0; i < 2; ++i) {
    k_radial<<<512, 256, 0, stream>>>(pos, shifts, snd, rcv, elist,
                                      i == 0 ? scal0 : scal1,
                                      W1 + (size_t)i * 8 * 64, W2 + (size_t)i * 64 * 64,
                                      W3 + (size_t)i * 64 * 64, h3, sedge, Ybuf,
                                      i == 0 ? 1 : 0);
    hipMemsetAsync(agg, 0, (size_t)N_NODES_C * 512 * 4, stream);
    k_gather<<<768, 256, 0, stream>>>(h3, W4 + (size_t)i * 64 * 512, Ybuf, sedge,
                                      tdesc, tstart + N_NODES_C, agg);
    k_node<<<N_NODES_C / 8, 256, 0, stream>>>(agg, nf, Wlin + (size_t)i * 4096,
                                              Wprod + (size_t)i * 4096,
                                              Wskip + (size_t)i * 8192,
                                              w2v + (size_t)i * 32, w3v + (size_t)i * 32,
                                              elem, scal1, out, i);
  }
}

// Round 14
// 437.632 us; speedup vs baseline: 1.8529x; 1.6257x over previous
//
#include <hip/hip_runtime.h>
#include <math.h>

#define N_NODES_C 16384
#define N_EDGES_C 196608
#define MAX_TILES 32768

typedef short bf16x8 __attribute__((ext_vector_type(8)));
typedef unsigned short u16x8 __attribute__((ext_vector_type(8)));
typedef float f32x4 __attribute__((ext_vector_type(4)));
typedef float f32x8 __attribute__((ext_vector_type(8)));

__device__ __forceinline__ float silu_f(float x) {
  return x * __builtin_amdgcn_rcpf(1.0f + __expf(-x));
}

// ---------------- CSR build ----------------
__global__ void k_count(const int* __restrict__ rcv, int* __restrict__ counts) {
  int e = blockIdx.x * 256 + threadIdx.x;
  atomicAdd(&counts[rcv[e]], 1);
}

// dual prefix sum: exact CSR offsets AND tile offsets (ceil(cnt/16))
__global__ __launch_bounds__(1024) void k_scan(const int* __restrict__ counts,
                                               int* __restrict__ row_start,
                                               int* __restrict__ cursor,
                                               int* __restrict__ tstart) {
  __shared__ int s1a[1024];
  __shared__ int s2a[1024];
  const int tid = threadIdx.x;
  int loc[16];
  int s1 = 0, s2 = 0;
#pragma unroll
  for (int i = 0; i < 16; ++i) {
    loc[i] = counts[tid * 16 + i];
    s1 += loc[i];
    s2 += (loc[i] + 15) >> 4;
  }
  s1a[tid] = s1;
  s2a[tid] = s2;
  __syncthreads();
  for (int off = 1; off < 1024; off <<= 1) {
    int t1 = (tid >= off) ? s1a[tid - off] : 0;
    int t2 = (tid >= off) ? s2a[tid - off] : 0;
    __syncthreads();
    s1a[tid] += t1;
    s2a[tid] += t2;
    __syncthreads();
  }
  int e1 = s1a[tid] - s1, e2 = s2a[tid] - s2;
#pragma unroll
  for (int i = 0; i < 16; ++i) {
    row_start[tid * 16 + i] = e1;
    cursor[tid * 16 + i] = e1;
    tstart[tid * 16 + i] = e2;
    e1 += loc[i];
    e2 += (loc[i] + 15) >> 4;
  }
  if (tid == 1023) {
    row_start[N_NODES_C] = e1;
    tstart[N_NODES_C] = e2;
  }
}

__global__ void k_fill(const int* __restrict__ rcv, int* __restrict__ cursor,
                       int* __restrict__ elist) {
  int e = blockIdx.x * 256 + threadIdx.x;
  int slot = atomicAdd(&cursor[rcv[e]], 1);
  elist[slot] = e;
}

// tile descriptors: x = node | len<<20 | multi<<31 ; y = p0 (CSR offset)
__global__ void k_tiles(const int* __restrict__ row_start, const int* __restrict__ tstart,
                        int2* __restrict__ tdesc) {
  const int n = blockIdx.x * 256 + threadIdx.x;
  const int e0 = row_start[n], e1 = row_start[n + 1];
  const int cnt = e1 - e0;
  const int nt = (cnt + 15) >> 4;
  const int t0 = tstart[n];
  const unsigned mbit = (nt > 1) ? 0x80000000u : 0u;
  for (int j = 0; j < nt; ++j) {
    int len = cnt - 16 * j;
    if (len > 16) len = 16;
    tdesc[t0 + j] = make_int2((int)((unsigned)n | ((unsigned)len << 20) | mbit), e0 + 16 * j);
  }
}

// zero agg rows ONLY for multi-tile (atomicAdd) and empty nodes; single-tile
// rows are fully overwritten by k_gather's plain store.
__global__ void k_zero(const int* __restrict__ row_start, float* __restrict__ agg) {
  const int n = blockIdx.x * 4 + (threadIdx.x >> 6);
  const int lane = threadIdx.x & 63;
  const int cnt = row_start[n + 1] - row_start[n];
  if (cnt > 16 || cnt == 0) {
    f32x4* ap = (f32x4*)&agg[(size_t)n * 512];
    const f32x4 z = {0.f, 0.f, 0.f, 0.f};
    ap[lane] = z;
    ap[lane + 64] = z;
  }
}

// ---------------- node element id + embedding ----------------
__global__ void k_elem(const float* __restrict__ attrs, int* __restrict__ elem) {
  int n = blockIdx.x * 256 + threadIdx.x;
  const float* a = attrs + n * 8;
  int best = 0;
  float bv = a[0];
#pragma unroll
  for (int z = 1; z < 8; ++z) {
    if (a[z] > bv) { bv = a[z]; best = z; }
  }
  elem[n] = best;
}

__global__ void k_embed(const float* __restrict__ attrs, const float* __restrict__ Wemb,
                        float* __restrict__ scal0, float* __restrict__ nf) {
  int gid = blockIdx.x * 256 + threadIdx.x;  // N*32 threads
  int n = gid >> 5, c = gid & 31;
  float s = 0.f;
#pragma unroll
  for (int z = 0; z < 8; ++z) s = fmaf(attrs[n * 8 + z], Wemb[z * 32 + c], s);
  scal0[gid] = s;
  float* row = nf + (size_t)n * 512 + c * 16;
  *(float4*)&row[0] = make_float4(s, 0.f, 0.f, 0.f);
  *(float4*)&row[4] = make_float4(0.f, 0.f, 0.f, 0.f);
  *(float4*)&row[8] = make_float4(0.f, 0.f, 0.f, 0.f);
  *(float4*)&row[12] = make_float4(0.f, 0.f, 0.f, 0.f);
}

// ---------------- per-edge radial MLP via MFMA (+SH, +s-edge) -------------
// Wave = 16 edges (one MFMA M-tile), 6 groups per wave, barrier-free.
// Y is written pre-scaled by 1/12 (AVG_NEIGH) — only k_gather consumes it.
__global__ __launch_bounds__(256, 2) void k_radial(
    const float* __restrict__ pos, const float* __restrict__ shifts,
    const int* __restrict__ snd, const int* __restrict__ rcv,
    const int* __restrict__ elist, const float* __restrict__ scal,
    const float* __restrict__ W1g, const float* __restrict__ W2g,
    const float* __restrict__ W3g, unsigned short* __restrict__ h3,
    float* __restrict__ sedge, float* __restrict__ Yout, const int writeY) {
  __shared__ unsigned tb[4][64 * 17];
  const int wid = threadIdx.x >> 6, lane = threadIdx.x & 63;
  const int grp = lane >> 4, lm = lane & 15;
  unsigned* tw = tb[wid];

  // ---- weight B-fragments (hi/lo bf16), loaded once per wave ----
  bf16x8 b1hi[4], b1lo[4];
#pragma unroll
  for (int t = 0; t < 4; ++t) {
#pragma unroll
    for (int j = 0; j < 8; ++j) {
      const float wv = (grp == 0) ? W1g[j * 64 + t * 16 + lm] : 0.f;
      const unsigned hb = __float_as_uint(wv) & 0xFFFF0000u;
      b1hi[t][j] = (short)(hb >> 16);
      b1lo[t][j] = (short)(__float_as_uint(wv - __uint_as_float(hb)) >> 16);
    }
  }
  bf16x8 b2hi[4][2], b2lo[4][2], b3hi[4][2], b3lo[4][2];
#pragma unroll
  for (int t = 0; t < 4; ++t) {
#pragma unroll
    for (int kf = 0; kf < 2; ++kf) {
#pragma unroll
      for (int j = 0; j < 8; ++j) {
        const int widx = (kf * 32 + grp * 8 + j) * 64 + t * 16 + lm;
        {
          const float wv = W2g[widx];
          const unsigned hb = __float_as_uint(wv) & 0xFFFF0000u;
          b2hi[t][kf][j] = (short)(hb >> 16);
          b2lo[t][kf][j] = (short)(__float_as_uint(wv - __uint_as_float(hb)) >> 16);
        }
        {
          const float wv = W3g[widx];
          const unsigned hb = __float_as_uint(wv) & 0xFFFF0000u;
          b3hi[t][kf][j] = (short)(hb >> 16);
          b3lo[t][kf][j] = (short)(__float_as_uint(wv - __uint_as_float(hb)) >> 16);
        }
      }
    }
  }

  const int wv_id = blockIdx.x * 4 + wid;  // 0..2047
  for (int g = 0; g < 6; ++g) {
    const int p0 = (wv_id * 6 + g) * 16;
    const int p = p0 + lm;
    const int e = elist[p];
    const int sn = snd[e], rc = rcv[e];
    const float vx = pos[rc * 3 + 0] - pos[sn * 3 + 0] + shifts[e * 3 + 0];
    const float vy = pos[rc * 3 + 1] - pos[sn * 3 + 1] + shifts[e * 3 + 1];
    const float vz = pos[rc * 3 + 2] - pos[sn * 3 + 2] + shifts[e * 3 + 2];
    const float len = __builtin_amdgcn_sqrtf(vx * vx + vy * vy + vz * vz + 1e-18f);
    const float u = len * 0.2f;  // / R_MAX
    float fc = 0.f;
    if (u < 1.0f) {
      const float u2 = u * u, u5 = u2 * u2 * u;
      fc = 1.0f - 21.0f * u5 + 35.0f * u5 * u - 15.0f * u5 * u2;
    }
    const float pref = 0.6324555320336759f * fc * __builtin_amdgcn_rcpf(fmaxf(len, 1e-9f));
    float ef[8];
#pragma unroll
    for (int k = 0; k < 8; ++k) {
      const float pin = 3.14159274f * (float)(k + 1);
      ef[k] = pref * __sinf(pin * u);
    }

    if (writeY) {
      const float il = __builtin_amdgcn_rcpf(len);
      const float x = vx * il, y = vy * il, z = vz * il;
      const float x2 = x * x, y2 = y * y, z2 = z * z;
      const float s3 = 1.7320508075688772f;
      const float s15 = 3.872983346207417f;
      const float s5h = 1.118033988749895f;
      const float s35_8 = 2.091650066335189f;
      const float s105 = 10.246950765959598f;
      const float s21_8 = 1.6201851746019651f;
      const float s7h = 1.3228756555322954f;
      const float s105h = 5.123475382979799f;
      float4 yq = make_float4(1.f, s3 * x, s3 * y, s3 * z);
      if (grp == 1)
        yq = make_float4(s15 * x * y, s15 * y * z, s5h * (3.f * z2 - 1.f), s15 * x * z);
      if (grp == 2)
        yq = make_float4(0.5f * s15 * (x2 - y2), s35_8 * y * (3.f * x2 - y2),
                         s105 * x * y * z, s21_8 * y * (5.f * z2 - 1.f));
      if (grp == 3)
        yq = make_float4(s7h * z * (5.f * z2 - 3.f), s21_8 * x * (5.f * z2 - 1.f),
                         s105h * z * (x2 - y2), s35_8 * x * (x2 - 3.f * y2));
      const float inv12 = 1.0f / 12.0f;  // AVG_NEIGH folded into Y
      yq.x *= inv12; yq.y *= inv12; yq.z *= inv12; yq.w *= inv12;
      *(float4*)&Yout[(size_t)p * 16 + grp * 4] = yq;
    }

    // sedge[p][32]: each of the 4 grp-lanes of edge lm writes its 8-col chunk
    {
      const float4 sa = *(const float4*)&scal[(size_t)sn * 32 + grp * 8];
      const float4 sb = *(const float4*)&scal[(size_t)sn * 32 + grp * 8 + 4];
      *(float4*)&sedge[(size_t)p * 32 + grp * 8] = sa;
      *(float4*)&sedge[(size_t)p * 32 + grp * 8 + 4] = sb;
    }

    // ---- layer 1: A-frag straight from ef (grp0 holds k=0..7, rest zero)
    bf16x8 a1hi, a1lo;
#pragma unroll
    for (int j = 0; j < 8; ++j) {
      const float v = (grp == 0) ? ef[j] : 0.f;
      const unsigned hb = __float_as_uint(v) & 0xFFFF0000u;
      a1hi[j] = (short)(hb >> 16);
      a1lo[j] = (short)(__float_as_uint(v - __uint_as_float(hb)) >> 16);
    }
    f32x4 acc[4];
#pragma unroll
    for (int t = 0; t < 4; ++t) {
      f32x4 a = {0.f, 0.f, 0.f, 0.f};
      a = __builtin_amdgcn_mfma_f32_16x16x32_bf16(a1hi, b1hi[t], a, 0, 0, 0);
      a = __builtin_amdgcn_mfma_f32_16x16x32_bf16(a1lo, b1hi[t], a, 0, 0, 0);
      a = __builtin_amdgcn_mfma_f32_16x16x32_bf16(a1hi, b1lo[t], a, 0, 0, 0);
      acc[t] = a;
    }
#pragma unroll
    for (int t = 0; t < 4; ++t)
#pragma unroll
      for (int r = 0; r < 4; ++r) {
        const float v = silu_f(acc[t][r]);
        const unsigned hb = __float_as_uint(v) & 0xFFFF0000u;
        tw[(t * 16 + lm) * 17 + grp * 4 + r] =
            hb | (__float_as_uint(v - __uint_as_float(hb)) >> 16);
      }
    // ---- read A2 (transpose via LDS) and layer 2
    bf16x8 a2h0, a2h1, a2l0, a2l1;
#pragma unroll
    for (int j = 0; j < 8; ++j) {
      const unsigned u0 = tw[(grp * 8 + j) * 17 + lm];
      const unsigned u1 = tw[(32 + grp * 8 + j) * 17 + lm];
      a2h0[j] = (short)(u0 >> 16);
      a2l0[j] = (short)(u0 & 0xFFFFu);
      a2h1[j] = (short)(u1 >> 16);
      a2l1[j] = (short)(u1 & 0xFFFFu);
    }
#pragma unroll
    for (int t = 0; t < 4; ++t) {
      f32x4 a = {0.f, 0.f, 0.f, 0.f};
      a = __builtin_amdgcn_mfma_f32_16x16x32_bf16(a2h0, b2hi[t][0], a, 0, 0, 0);
      a = __builtin_amdgcn_mfma_f32_16x16x32_bf16(a2h1, b2hi[t][1], a, 0, 0, 0);
      a = __builtin_amdgcn_mfma_f32_16x16x32_bf16(a2l0, b2hi[t][0], a, 0, 0, 0);
      a = __builtin_amdgcn_mfma_f32_16x16x32_bf16(a2l1, b2hi[t][1], a, 0, 0, 0);
      a = __builtin_amdgcn_mfma_f32_16x16x32_bf16(a2h0, b2lo[t][0], a, 0, 0, 0);
      a = __builtin_amdgcn_mfma_f32_16x16x32_bf16(a2h1, b2lo[t][1], a, 0, 0, 0);
      acc[t] = a;
    }
#pragma unroll
    for (int t = 0; t < 4; ++t)
#pragma unroll
      for (int r = 0; r < 4; ++r) {
        const float v = silu_f(acc[t][r]);
        const unsigned hb = __float_as_uint(v) & 0xFFFF0000u;
        tw[(t * 16 + lm) * 17 + grp * 4 + r] =
            hb | (__float_as_uint(v - __uint_as_float(hb)) >> 16);
      }
    // ---- read A3 and layer 3
    bf16x8 a3h0, a3h1, a3l0, a3l1;
#pragma unroll
    for (int j = 0; j < 8; ++j) {
      const unsigned u0 = tw[(grp * 8 + j) * 17 + lm];
      const unsigned u1 = tw[(32 + grp * 8 + j) * 17 + lm];
      a3h0[j] = (short)(u0 >> 16);
      a3l0[j] = (short)(u0 & 0xFFFFu);
      a3h1[j] = (short)(u1 >> 16);
      a3l1[j] = (short)(u1 & 0xFFFFu);
    }
#pragma unroll
    for (int t = 0; t < 4; ++t) {
      f32x4 a = {0.f, 0.f, 0.f, 0.f};
      a = __builtin_amdgcn_mfma_f32_16x16x32_bf16(a3h0, b3hi[t][0], a, 0, 0, 0);
      a = __builtin_amdgcn_mfma_f32_16x16x32_bf16(a3h1, b3hi[t][1], a, 0, 0, 0);
      a = __builtin_amdgcn_mfma_f32_16x16x32_bf16(a3l0, b3hi[t][0], a, 0, 0, 0);
      a = __builtin_amdgcn_mfma_f32_16x16x32_bf16(a3l1, b3hi[t][1], a, 0, 0, 0);
      a = __builtin_amdgcn_mfma_f32_16x16x32_bf16(a3h0, b3lo[t][0], a, 0, 0, 0);
      a = __builtin_amdgcn_mfma_f32_16x16x32_bf16(a3h1, b3lo[t][1], a, 0, 0, 0);
      acc[t] = a;
    }
#pragma unroll
    for (int t = 0; t < 4; ++t)
#pragma unroll
      for (int r = 0; r < 4; ++r) {
        const float v = silu_f(acc[t][r]);
        const unsigned hb = __float_as_uint(v) & 0xFFFF0000u;
        tw[(t * 16 + lm) * 17 + grp * 4 + r] =
            hb | (__float_as_uint(v - __uint_as_float(hb)) >> 16);
      }
    // ---- coalesced h3 writeout: lane = (edge eo, quarter q)
    {
      const int eo = lane >> 2, q = lane & 3;
      unsigned short* hrow = h3 + (size_t)(p0 + eo) * 128;
      u16x8 h0, h1, l0v, l1v;
#pragma unroll
      for (int j = 0; j < 8; ++j) {
        const unsigned ua = tw[(q * 16 + j) * 17 + eo];
        const unsigned ub = tw[(q * 16 + 8 + j) * 17 + eo];
        h0[j] = (unsigned short)(ua >> 16);
        l0v[j] = (unsigned short)(ua & 0xFFFFu);
        h1[j] = (unsigned short)(ub >> 16);
        l1v[j] = (unsigned short)(ub & 0xFFFFu);
      }
      *(u16x8*)(hrow + q * 16) = h0;
      *(u16x8*)(hrow + q * 16 + 8) = h1;
      *(u16x8*)(hrow + 64 + q * 16) = l0v;
      *(u16x8*)(hrow + 64 + q * 16 + 8) = l1v;
    }
  }
}

// ---------------- W4 GEMM via MFMA, depth-4 ring pipeline -----------------
// EXACT R11 config: launch_bounds(256,2), grid 1024, 512 XCD-paired streams.
// (256,3)/(256,4) both SPILL the ring (VGPR 108->84/64, FETCH 47->120/792MB)
// — unified VGPR+AGPR budget can't fit 3 waves/EU. Do not re-raise.
#define MLOAD(K, tix)                                                         \
  {                                                                           \
    const int tic = ((tix) < ntiles) ? (tix) : (ntiles - 1);                  \
    const int2 td = tdesc[tic];                                               \
    M[K] = (unsigned)td.x;                                                    \
    P[K] = td.y;                                                              \
  }

#define DLOAD(K2)                                                             \
  {                                                                           \
    const int p0 = P[K2];                                                     \
    const int lend = (int)((M[K2] >> 20) & 31u);                              \
    const unsigned short* hp = h3 + (size_t)(p0 + lm) * 128 + grp * 8;        \
    A[K2][0] = *(const bf16x8*)(hp);                                          \
    A[K2][1] = *(const bf16x8*)(hp + 32);                                     \
    A[K2][2] = *(const bf16x8*)(hp + 64);                                     \
    A[K2][3] = *(const bf16x8*)(hp + 96);                                     \
    _Pragma("unroll") for (int r = 0; r < 4; ++r) {                           \
      const int rr = grp * 4 + r;                                             \
      const int pr = p0 + rr;                                                 \
      const float yr = Yb[(size_t)pr * 16 + lm];                              \
      const float Yv = (rr < lend) ? yr : 0.f;                                \
      const float4 s4 = *(const float4*)&sedge[(size_t)pr * 32 + cg * 4];     \
      YS[K2][r][0] = Yv * s4.x;                                               \
      YS[K2][r][1] = Yv * s4.y;                                               \
      YS[K2][r][2] = Yv * s4.z;                                               \
      YS[K2][r][3] = Yv * s4.w;                                               \
    }                                                                         \
  }

#define STEP(K)                                                               \
  {                                                                           \
    const unsigned mcur = M[K];                                               \
    MLOAD(K, tb + 4);                                                         \
    DLOAD((K + 2) & 3);                                                       \
    const int node = (int)(mcur & 0x3FFFu);                                   \
    const bool multi = (mcur & 0x80000000u) != 0u;                            \
    float outv[4];                                                            \
    _Pragma("unroll") for (int t = 0; t < 4; ++t) {                           \
      f32x4 acc = {0.f, 0.f, 0.f, 0.f};                                       \
      acc = __builtin_amdgcn_mfma_f32_16x16x32_bf16(A[K][0], bhi[t][0], acc, 0, 0, 0); \
      acc = __builtin_amdgcn_mfma_f32_16x16x32_bf16(A[K][1], bhi[t][1], acc, 0, 0, 0); \
      acc = __builtin_amdgcn_mfma_f32_16x16x32_bf16(A[K][2], bhi[t][0], acc, 0, 0, 0); \
      acc = __builtin_amdgcn_mfma_f32_16x16x32_bf16(A[K][3], bhi[t][1], acc, 0, 0, 0); \
      acc = __builtin_amdgcn_mfma_f32_16x16x32_bf16(A[K][0], blo[t][0], acc, 0, 0, 0); \
      acc = __builtin_amdgcn_mfma_f32_16x16x32_bf16(A[K][1], blo[t][1], acc, 0, 0, 0); \
      float cp = acc[0] * YS[K][0][t];                                        \
      cp = fmaf(acc[1], YS[K][1][t], cp);                                     \
      cp = fmaf(acc[2], YS[K][2][t], cp);                                     \
      cp = fmaf(acc[3], YS[K][3][t], cp);                                     \
      cp += __shfl_xor(cp, 16);                                               \
      cp += __shfl_xor(cp, 32);                                               \
      outv[t] = cp;                                                           \
    }                                                                         \
    float sel = outv[0];                                                      \
    sel = (grp == 1) ? outv[1] : sel;                                         \
    sel = (grp == 2) ? outv[2] : sel;                                         \
    sel = (grp == 3) ? outv[3] : sel;                                         \
    if (tb < ntiles) {                                                        \
      float* ap = &agg[(size_t)node * 512 + cg * 64 + grp * 16 + lm];         \
      if (multi)                                                              \
        atomicAdd(ap, sel);                                                   \
      else                                                                    \
        *ap = sel;                                                            \
    }                                                                         \
    ++tb;                                                                     \
  }

__global__ __launch_bounds__(256, 2) void k_gather(
    const unsigned short* __restrict__ h3, const float* __restrict__ W4g,
    const float* __restrict__ Yb, const float* __restrict__ sedge,
    const int2* __restrict__ tdesc, const int* __restrict__ ntiles_ptr,
    float* __restrict__ agg) {
  const int bid = blockIdx.x;
  const int xcd = bid & 7, q = bid >> 3, half = q & 1;
  const int s = ((q >> 1) << 3) | xcd;          // stream 0..511
  const int w = threadIdx.x >> 6, lane = threadIdx.x & 63;
  const int grp = lane >> 4, lm = lane & 15;
  const int cg = half * 4 + w;                  // col group 0..7 (64 cols)

  bf16x8 bhi[4][2], blo[4][2];
#pragma unroll
  for (int t = 0; t < 4; ++t) {
    const int col = cg * 64 + t * 16 + lm;
#pragma unroll
    for (int kk = 0; kk < 2; ++kk) {
#pragma unroll
      for (int j = 0; j < 8; ++j) {
        const float wv = W4g[(kk * 32 + grp * 8 + j) * 512 + col];
        const unsigned hb = __float_as_uint(wv) & 0xFFFF0000u;
        bhi[t][kk][j] = (short)(hb >> 16);
        blo[t][kk][j] = (short)(__float_as_uint(wv - __uint_as_float(hb)) >> 16);
      }
    }
  }

  const int ntiles = *ntiles_ptr;
  const int chunk4 = ((((ntiles + 511) >> 9) + 3) & ~3);
  int tb = s * chunk4;

  bf16x8 A[4][4];
  float YS[4][4][4];
  unsigned M[4];
  int P[4];

  MLOAD(0, tb + 0);
  MLOAD(1, tb + 1);
  MLOAD(2, tb + 2);
  MLOAD(3, tb + 3);
  DLOAD(0);
  DLOAD(1);

  for (int jj = 0; jj < chunk4; jj += 4) {
    STEP(0);
    STEP(1);
    STEP(2);
    STEP(3);
  }
}

// ---------------- per-node: Wlin, quadratic, Wprod + skip, desc out -------
__global__ __launch_bounds__(256) void k_node(
    const float* __restrict__ agg, float* __restrict__ nf,
    const float* __restrict__ Wlin, const float* __restrict__ Wprod,
    const float* __restrict__ Wskip, const float* __restrict__ w2v,
    const float* __restrict__ w3v, const int* __restrict__ elem,
    float* __restrict__ scal_out, float* __restrict__ dout, const int layer) {
  __shared__ __align__(16) float aggs[8][512];
  __shared__ __align__(16) float nfs[8][512];
  __shared__ float bs[8][544];  // pitch 17 per channel row
  const int tid = threadIdx.x;
  const int n0 = blockIdx.x * 8;
  for (int i = tid; i < 1024; i += 256) {
    const int nl = i >> 7, qq = i & 127;
    ((f32x4*)aggs)[i] = ((const f32x4*)agg)[(size_t)(n0 + nl) * 128 + qq];
    ((f32x4*)nfs)[i] = ((const f32x4*)nf)[(size_t)(n0 + nl) * 128 + qq];
  }
  __syncthreads();
  const int nl = tid >> 5, o = tid & 31;
  const int n = n0 + nl;
  constexpr int SLa[4] = {0, 1, 4, 9};
  constexpr int ELa[4] = {1, 4, 9, 16};
  float a[16];
#pragma unroll
  for (int m = 0; m < 16; ++m) a[m] = 0.f;
#pragma unroll
  for (int l = 0; l < 4; ++l) {
    for (int c = 0; c < 32; ++c) {
      const float w = Wlin[(l * 32 + c) * 32 + o];
#pragma unroll
      for (int m = SLa[l]; m < ELa[l]; ++m) a[m] = fmaf(aggs[nl][c * 16 + m], w, a[m]);
    }
  }
  const float inv = a[0];
  float p2 = 0.f;
#pragma unroll
  for (int m = 0; m < 16; ++m) p2 = fmaf(a[m], a[m], p2);
  a[0] = inv + w2v[o] * p2 + w3v[o] * inv * p2;
#pragma unroll
  for (int m = 0; m < 16; ++m) bs[nl][o * 17 + m] = a[m];
  __syncthreads();
  float outv[16];
#pragma unroll
  for (int m = 0; m < 16; ++m) outv[m] = 0.f;
#pragma unroll
  for (int l = 0; l < 4; ++l) {
    for (int c = 0; c < 32; ++c) {
      const float w = Wprod[(l * 32 + c) * 32 + o];
#pragma unroll
      for (int m = SLa[l]; m < ELa[l]; ++m) outv[m] = fmaf(bs[nl][c * 17 + m], w, outv[m]);
    }
  }
  const int z = elem[n];
  const float* wsk = Wskip + z * 1024;
  for (int c = 0; c < 32; ++c) {
    const float w = wsk[c * 32 + o];
#pragma unroll
    for (int m = 0; m < 16; ++m) outv[m] = fmaf(nfs[nl][c * 16 + m], w, outv[m]);
  }
  float* op = nf + (size_t)n * 512 + o * 16;
  *(float4*)&op[0] = make_float4(outv[0], outv[1], outv[2], outv[3]);
  *(float4*)&op[4] = make_float4(outv[4], outv[5], outv[6], outv[7]);
  *(float4*)&op[8] = make_float4(outv[8], outv[9], outv[10], outv[11]);
  *(float4*)&op[12] = make_float4(outv[12], outv[13], outv[14], outv[15]);
  scal_out[n * 32 + o] = outv[0];
  dout[(size_t)n * 64 + layer * 32 + o] = outv[0];
}

extern "C" void kernel_launch(void* const* d_in, const int* in_sizes, int n_in,
                              void* d_out, int out_size, void* d_ws, size_t ws_size,
                              hipStream_t stream) {
  const float* pos = (const float*)d_in[0];
  const float* attrs = (const float*)d_in[1];
  const float* shifts = (const float*)d_in[2];
  const int* eidx = (const int*)d_in[3];
  const float* W_embed = (const float*)d_in[4];
  const float* W1 = (const float*)d_in[5];
  const float* W2 = (const float*)d_in[6];
  const float* W3 = (const float*)d_in[7];
  const float* W4 = (const float*)d_in[8];
  const float* Wlin = (const float*)d_in[9];
  const float* Wskip = (const float*)d_in[10];
  const float* w2v = (const float*)d_in[11];
  const float* w3v = (const float*)d_in[12];
  const float* Wprod = (const float*)d_in[13];
  float* out = (float*)d_out;
  const int* snd = eidx;
  const int* rcv = eidx + N_EDGES_C;

  char* p = (char*)d_ws;
  auto take = [&](size_t bytes) {
    char* q = p;
    p += (bytes + 255) & ~(size_t)255;
    return q;
  };
  int* counts = (int*)take((size_t)N_NODES_C * 4);
  int* row_start = (int*)take((size_t)(N_NODES_C + 1) * 4);
  int* cursor = (int*)take((size_t)N_NODES_C * 4);
  int* tstart = (int*)take((size_t)(N_NODES_C + 1) * 4);
  int* elist = (int*)take((size_t)N_EDGES_C * 4);
  int2* tdesc = (int2*)take((size_t)MAX_TILES * 8);
  int* elem = (int*)take((size_t)N_NODES_C * 4);
  float* Ybuf = (float*)take((size_t)(N_EDGES_C + 16) * 16 * 4);
  unsigned short* h3 = (unsigned short*)take((size_t)(N_EDGES_C + 16) * 128 * 2);
  float* sedge = (float*)take((size_t)(N_EDGES_C + 16) * 32 * 4);
  float* agg = (float*)take((size_t)N_NODES_C * 512 * 4);
  float* nf = (float*)take((size_t)N_NODES_C * 512 * 4);
  float* scal0 = (float*)take((size_t)N_NODES_C * 32 * 4);
  float* scal1 = (float*)take((size_t)N_NODES_C * 32 * 4);
  (void)ws_size; (void)in_sizes; (void)n_in; (void)out_size;

  hipMemsetAsync(counts, 0, (size_t)N_NODES_C * 4, stream);
  k_count<<<N_EDGES_C / 256, 256, 0, stream>>>(rcv, counts);
  k_scan<<<1, 1024, 0, stream>>>(counts, row_start, cursor, tstart);
  k_fill<<<N_EDGES_C / 256, 256, 0, stream>>>(rcv, cursor, elist);
  k_tiles<<<N_NODES_C / 256, 256, 0, stream>>>(row_start, tstart, tdesc);
  k_elem<<<N_NODES_C / 256, 256, 0, stream>>>(attrs, elem);
  k_embed<<<N_NODES_C * 32 / 256, 256, 0, stream>>>(attrs, W_embed, scal0, nf);

  for (int i = 0; i < 2; ++i) {
    k_radial<<<512, 256, 0, stream>>>(pos, shifts, snd, rcv, elist,
                                      i == 0 ? scal0 : scal1,
                                      W1 + (size_t)i * 8 * 64, W2 + (size_t)i * 64 * 64,
                                      W3 + (size_t)i * 64 * 64, h3, sedge, Ybuf,
                                      i == 0 ? 1 : 0);
    k_zero<<<N_NODES_C / 4, 256, 0, stream>>>(row_start, agg);
    k_gather<<<1024, 256, 0, stream>>>(h3, W4 + (size_t)i * 64 * 512, Ybuf, sedge,
                                       tdesc, tstart + N_NODES_C, agg);
    k_node<<<N_NODES_C / 8, 256, 0, stream>>>(agg, nf, Wlin + (size_t)i * 4096,
                                              Wprod + (size_t)i * 4096,
                                              Wskip + (size_t)i * 8192,
                                              w2v + (size_t)i * 32, w3v + (size_t)i * 32,
                                              elem, scal1, out, i);
  }
}